// Round 1
// baseline (1611.947 us; speedup 1.0000x reference)
//
#include <hip/hip_runtime.h>
#include <math.h>

#define NN 100000
#define NE 3200000
#define NG 512

// ---------------- degree / normalization ----------------
__global__ void deg_init_kernel(float* deg, int n) {
    int i = blockIdx.x * blockDim.x + threadIdx.x;
    if (i < n) deg[i] = 1.0f;  // self-loop
}

__global__ void deg_count_kernel(const int* __restrict__ dst, float* deg, int e) {
    int i = blockIdx.x * blockDim.x + threadIdx.x;
    if (i < e) atomicAdd(&deg[dst[i]], 1.0f);
}

__global__ void dinv_kernel(float* deg, int n) {
    int i = blockIdx.x * blockDim.x + threadIdx.x;
    if (i < n) deg[i] = rsqrtf(deg[i]);
}

// ---------------- t[n,32] = x[n,128] @ W[128,32] ----------------
__global__ void gemm128_32_kernel(const float* __restrict__ x, const float* __restrict__ W,
                                  float* __restrict__ t, int n) {
    __shared__ float Wl[128 * 32];
    for (int i = threadIdx.x; i < 128 * 32; i += blockDim.x) Wl[i] = W[i];
    __syncthreads();
    int node = blockIdx.x * blockDim.x + threadIdx.x;
    if (node >= n) return;
    float acc[32];
#pragma unroll
    for (int k = 0; k < 32; k++) acc[k] = 0.f;
    const float4* xp = (const float4*)(x + (long long)node * 128);
    for (int j4 = 0; j4 < 32; j4++) {
        float4 v4 = xp[j4];
        float vv[4] = {v4.x, v4.y, v4.z, v4.w};
#pragma unroll
        for (int c = 0; c < 4; c++) {
            const float* wr = &Wl[(j4 * 4 + c) * 32];
#pragma unroll
            for (int k = 0; k < 32; k++) acc[k] += vv[c] * wr[k];
        }
    }
    float4* op = (float4*)(t + (long long)node * 32);
#pragma unroll
    for (int k4 = 0; k4 < 8; k4++)
        op[k4] = make_float4(acc[4 * k4], acc[4 * k4 + 1], acc[4 * k4 + 2], acc[4 * k4 + 3]);
}

// ---------------- t[n,32] = xin[n,32] @ W[32,32] ----------------
__global__ void gemm32_32_kernel(const float* __restrict__ xin, const float* __restrict__ W,
                                 float* __restrict__ t, int n) {
    __shared__ float Wl[32 * 32];
    for (int i = threadIdx.x; i < 32 * 32; i += blockDim.x) Wl[i] = W[i];
    __syncthreads();
    int node = blockIdx.x * blockDim.x + threadIdx.x;
    if (node >= n) return;
    float acc[32];
#pragma unroll
    for (int k = 0; k < 32; k++) acc[k] = 0.f;
    const float4* xp = (const float4*)(xin + (long long)node * 32);
#pragma unroll
    for (int j4 = 0; j4 < 8; j4++) {
        float4 v4 = xp[j4];
        float vv[4] = {v4.x, v4.y, v4.z, v4.w};
#pragma unroll
        for (int c = 0; c < 4; c++) {
            const float* wr = &Wl[(j4 * 4 + c) * 32];
#pragma unroll
            for (int k = 0; k < 32; k++) acc[k] += vv[c] * wr[k];
        }
    }
    float4* op = (float4*)(t + (long long)node * 32);
#pragma unroll
    for (int k4 = 0; k4 < 8; k4++)
        op[k4] = make_float4(acc[4 * k4], acc[4 * k4 + 1], acc[4 * k4 + 2], acc[4 * k4 + 3]);
}

// ---------------- agg = t * dinv^2  (self-loop term) ----------------
__global__ void selfscale_kernel(const float* __restrict__ t, const float* __restrict__ dinv,
                                 float* __restrict__ agg, long long total) {
    long long i = (long long)blockIdx.x * blockDim.x + threadIdx.x;
    if (i < total) {
        float d = dinv[i >> 5];
        agg[i] = t[i] * d * d;
    }
}

// ---------------- edge scatter: agg[dst] += t[src] * dinv[src]*dinv[dst] ----------------
__global__ void scatter_kernel(const int* __restrict__ src, const int* __restrict__ dst,
                               const float* __restrict__ dinv, const float* __restrict__ t,
                               float* agg, long long total) {
    long long stride = (long long)gridDim.x * blockDim.x;
    for (long long tid = (long long)blockIdx.x * blockDim.x + threadIdx.x; tid < total;
         tid += stride) {
        int e = (int)(tid >> 5);
        int k = (int)(tid & 31);
        int s = src[e];
        int d = dst[e];
        float nrm = dinv[s] * dinv[d];
        atomicAdd(&agg[(long long)d * 32 + k], t[(long long)s * 32 + k] * nrm);
    }
}

// ---------------- xo = relu(agg + b) ----------------
__global__ void biasrelu_kernel(const float* __restrict__ agg, const float* __restrict__ b,
                                float* __restrict__ xo, long long total) {
    long long i = (long long)blockIdx.x * blockDim.x + threadIdx.x;
    if (i < total) xo[i] = fmaxf(agg[i] + b[i & 31], 0.f);
}

// ---------------- h64 = relu(concat(x1,x2,x3) @ fc1_w + fc1_b) ----------------
__global__ void fc1_kernel(const float* __restrict__ x1, const float* __restrict__ x2,
                           const float* __restrict__ x3, const float* __restrict__ W,
                           const float* __restrict__ b, float* __restrict__ h64, int n) {
    __shared__ float Wl[96 * 64];
    for (int i = threadIdx.x; i < 96 * 64; i += blockDim.x) Wl[i] = W[i];
    __syncthreads();
    int node = blockIdx.x * blockDim.x + threadIdx.x;
    if (node >= n) return;
    float acc[64];
#pragma unroll
    for (int k = 0; k < 64; k++) acc[k] = b[k];
    const float* srcs[3] = {x1 + (long long)node * 32, x2 + (long long)node * 32,
                            x3 + (long long)node * 32};
    for (int s = 0; s < 3; s++) {
        const float* xp = srcs[s];
        for (int j = 0; j < 32; j++) {
            float v = xp[j];
            const float* wr = &Wl[(s * 32 + j) * 64];
#pragma unroll
            for (int k = 0; k < 64; k++) acc[k] += v * wr[k];
        }
    }
    float4* op = (float4*)(h64 + (long long)node * 64);
#pragma unroll
    for (int k4 = 0; k4 < 16; k4++)
        op[k4] = make_float4(fmaxf(acc[4 * k4], 0.f), fmaxf(acc[4 * k4 + 1], 0.f),
                             fmaxf(acc[4 * k4 + 2], 0.f), fmaxf(acc[4 * k4 + 3], 0.f));
}

// ---------------- h128 = relu(h64 @ fc2a_w + fc2a_b) ----------------
__global__ void fc2a_kernel(const float* __restrict__ h64, const float* __restrict__ W,
                            const float* __restrict__ b, float* __restrict__ h128, int n) {
    __shared__ float Wl[64 * 128];
    for (int i = threadIdx.x; i < 64 * 128; i += blockDim.x) Wl[i] = W[i];
    __syncthreads();
    int node = blockIdx.x * blockDim.x + threadIdx.x;
    if (node >= n) return;
    float acc[128];
#pragma unroll
    for (int k = 0; k < 128; k++) acc[k] = b[k];
    const float* xp = h64 + (long long)node * 64;
    for (int j = 0; j < 64; j++) {
        float v = xp[j];
        const float* wr = &Wl[j * 128];
#pragma unroll
        for (int k = 0; k < 128; k++) acc[k] += v * wr[k];
    }
    float4* op = (float4*)(h128 + (long long)node * 128);
#pragma unroll
    for (int k4 = 0; k4 < 32; k4++)
        op[k4] = make_float4(fmaxf(acc[4 * k4], 0.f), fmaxf(acc[4 * k4 + 1], 0.f),
                             fmaxf(acc[4 * k4 + 2], 0.f), fmaxf(acc[4 * k4 + 3], 0.f));
}

// ---------------- pooled[g,128] = sum over nodes of graph g (batch sorted) ----------------
__global__ void pool_kernel(const float* __restrict__ h128, const int* __restrict__ batch,
                            float* __restrict__ pooled, int n) {
    int g = blockIdx.x;
    // lower_bound(batch, g)
    int lo = 0, hi = n;
    while (lo < hi) {
        int mid = (lo + hi) >> 1;
        if (batch[mid] < g) lo = mid + 1; else hi = mid;
    }
    int start = lo;
    lo = start; hi = n;
    while (lo < hi) {
        int mid = (lo + hi) >> 1;
        if (batch[mid] < g + 1) lo = mid + 1; else hi = mid;
    }
    int end = lo;
    int k = threadIdx.x;  // 128 threads
    float s = 0.f;
    for (int i = start; i < end; i++) s += h128[(long long)i * 128 + k];
    pooled[g * 128 + k] = s;
}

// ---------------- head: relu(pooled@fc2b+b) @ fc3 + b3 -> log_softmax ----------------
__global__ void head_kernel(const float* __restrict__ pooled, const float* __restrict__ W2b,
                            const float* __restrict__ b2b, const float* __restrict__ W3,
                            const float* __restrict__ b3, float* __restrict__ out) {
    __shared__ float Wl[128 * 64];
    for (int i = threadIdx.x; i < 128 * 64; i += blockDim.x) Wl[i] = W2b[i];
    __syncthreads();
    int g = blockIdx.x * blockDim.x + threadIdx.x;
    if (g >= NG) return;
    float acc[64];
#pragma unroll
    for (int k = 0; k < 64; k++) acc[k] = b2b[k];
    const float* p = pooled + g * 128;
    for (int j = 0; j < 128; j++) {
        float v = p[j];
        const float* wr = &Wl[j * 64];
#pragma unroll
        for (int k = 0; k < 64; k++) acc[k] += v * wr[k];
    }
    float l0 = b3[0], l1 = b3[1];
#pragma unroll
    for (int k = 0; k < 64; k++) {
        float h = fmaxf(acc[k], 0.f);
        l0 += h * W3[k * 2 + 0];
        l1 += h * W3[k * 2 + 1];
    }
    float m = fmaxf(l0, l1);
    float lse = m + logf(expf(l0 - m) + expf(l1 - m));
    out[g * 2 + 0] = l0 - lse;
    out[g * 2 + 1] = l1 - lse;
}

extern "C" void kernel_launch(void* const* d_in, const int* in_sizes, int n_in,
                              void* d_out, int out_size, void* d_ws, size_t ws_size,
                              hipStream_t stream) {
    const float* x     = (const float*)d_in[0];
    const int*   ei    = (const int*)d_in[1];
    const int*   srcI  = ei;
    const int*   dstI  = ei + NE;
    const int*   batch = (const int*)d_in[2];
    const float* W1    = (const float*)d_in[3];
    const float* b1    = (const float*)d_in[4];
    const float* W2    = (const float*)d_in[5];
    const float* b2    = (const float*)d_in[6];
    const float* W3w   = (const float*)d_in[7];
    const float* b3w   = (const float*)d_in[8];
    const float* fc1w  = (const float*)d_in[9];
    const float* fc1b  = (const float*)d_in[10];
    const float* fc2aw = (const float*)d_in[11];
    const float* fc2ab = (const float*)d_in[12];
    const float* fc2bw = (const float*)d_in[13];
    const float* fc2bb = (const float*)d_in[14];
    const float* fc3w  = (const float*)d_in[15];
    const float* fc3b  = (const float*)d_in[16];
    float* out = (float*)d_out;

    float* ws   = (float*)d_ws;
    float* dinv = ws;                        // NN
    float* t    = dinv + NN;                 // NN*32
    float* agg  = t + (long long)NN * 32;    // NN*32
    float* x1   = agg + (long long)NN * 32;  // NN*32
    float* x2   = x1 + (long long)NN * 32;   // NN*32
    float* x3   = x2 + (long long)NN * 32;   // NN*32
    float* h64  = t;                         // reuse t+agg region (NN*64)
    float* h128 = x3 + (long long)NN * 32;   // NN*128
    float* pooled = h128 + (long long)NN * 128;  // NG*128

    const int thr = 256;
    int gN  = (NN + thr - 1) / thr;
    int gE  = (NE + thr - 1) / thr;
    long long n32 = (long long)NN * 32;
    int gN32 = (int)((n32 + thr - 1) / thr);

    // normalization
    deg_init_kernel<<<gN, thr, 0, stream>>>(dinv, NN);
    deg_count_kernel<<<gE, thr, 0, stream>>>(dstI, dinv, NE);
    dinv_kernel<<<gN, thr, 0, stream>>>(dinv, NN);

    long long e32 = (long long)NE * 32;

    // conv layer 1
    gemm128_32_kernel<<<gN, thr, 0, stream>>>(x, W1, t, NN);
    selfscale_kernel<<<gN32, thr, 0, stream>>>(t, dinv, agg, n32);
    scatter_kernel<<<16384, thr, 0, stream>>>(srcI, dstI, dinv, t, agg, e32);
    biasrelu_kernel<<<gN32, thr, 0, stream>>>(agg, b1, x1, n32);

    // conv layer 2
    gemm32_32_kernel<<<gN, thr, 0, stream>>>(x1, W2, t, NN);
    selfscale_kernel<<<gN32, thr, 0, stream>>>(t, dinv, agg, n32);
    scatter_kernel<<<16384, thr, 0, stream>>>(srcI, dstI, dinv, t, agg, e32);
    biasrelu_kernel<<<gN32, thr, 0, stream>>>(agg, b2, x2, n32);

    // conv layer 3
    gemm32_32_kernel<<<gN, thr, 0, stream>>>(x2, W3w, t, NN);
    selfscale_kernel<<<gN32, thr, 0, stream>>>(t, dinv, agg, n32);
    scatter_kernel<<<16384, thr, 0, stream>>>(srcI, dstI, dinv, t, agg, e32);
    biasrelu_kernel<<<gN32, thr, 0, stream>>>(agg, b3w, x3, n32);

    // MLP head (per node)
    fc1_kernel<<<gN, thr, 0, stream>>>(x1, x2, x3, fc1w, fc1b, h64, NN);
    fc2a_kernel<<<gN, thr, 0, stream>>>(h64, fc2aw, fc2ab, h128, NN);

    // pooling + classifier
    pool_kernel<<<NG, 128, 0, stream>>>(h128, batch, pooled, NN);
    head_kernel<<<(NG + thr - 1) / thr, thr, 0, stream>>>(pooled, fc2bw, fc2bb, fc3w, fc3b, out);
}

// Round 2
// 1195.006 us; speedup vs baseline: 1.3489x; 1.3489x over previous
//
#include <hip/hip_runtime.h>
#include <math.h>

#define NN 100000
#define NE 3200000
#define NG 512
#define NSPLIT 4
#define SCAN_BLOCK 256
#define SCAN_ELEMS 1024
#define NBLK ((NN + SCAN_ELEMS - 1) / SCAN_ELEMS)

// ---------------- zero int arrays ----------------
__global__ void zero2_kernel(int* a, int* b, int n) {
    int i = blockIdx.x * blockDim.x + threadIdx.x;
    if (i < n) { a[i] = 0; b[i] = 0; }
}

// ---------------- int degree histogram over dst ----------------
__global__ void deg_count_kernel(const int* __restrict__ dst, int* deg, int e) {
    int i = blockIdx.x * blockDim.x + threadIdx.x;
    if (i < e) atomicAdd(&deg[dst[i]], 1);
}

// ---------------- dinv = rsqrt(deg_edges + 1)  (self-loop) ----------------
__global__ void dinv_kernel(const int* __restrict__ deg, float* dinv, int n) {
    int i = blockIdx.x * blockDim.x + threadIdx.x;
    if (i < n) dinv[i] = rsqrtf((float)(deg[i] + 1));
}

// ---------------- scan pass 1: per-block inclusive scan -> rowptr[i+1], block sums ----------------
__global__ void scan1_kernel(const int* __restrict__ deg, int* __restrict__ rowptr,
                             int* __restrict__ bsums, int n) {
    __shared__ int lds[SCAN_BLOCK];
    int base = blockIdx.x * SCAN_ELEMS;
    int t = threadIdx.x;
    int v[4];
    int s = 0;
#pragma unroll
    for (int j = 0; j < 4; j++) {
        int i = base + t * 4 + j;
        v[j] = (i < n) ? deg[i] : 0;
        s += v[j];
    }
    lds[t] = s;
    __syncthreads();
    for (int off = 1; off < SCAN_BLOCK; off <<= 1) {
        int val = (t >= off) ? lds[t - off] : 0;
        __syncthreads();
        lds[t] += val;
        __syncthreads();
    }
    int run = (t > 0) ? lds[t - 1] : 0;
    if (t == SCAN_BLOCK - 1) bsums[blockIdx.x] = lds[t];
#pragma unroll
    for (int j = 0; j < 4; j++) {
        int i = base + t * 4 + j;
        run += v[j];
        if (i < n) rowptr[i + 1] = run;
    }
}

// ---------------- scan pass 2: serial exclusive scan of block sums ----------------
__global__ void scan2_kernel(int* bsums, int nb) {
    if (threadIdx.x == 0 && blockIdx.x == 0) {
        int acc = 0;
        for (int b = 0; b < nb; b++) { int v = bsums[b]; bsums[b] = acc; acc += v; }
    }
}

// ---------------- scan pass 3: add block offsets ----------------
__global__ void scan3_kernel(int* rowptr, const int* __restrict__ bsums, int n) {
    int i = blockIdx.x * blockDim.x + threadIdx.x;
    if (i == 0) rowptr[0] = 0;
    if (i < n) rowptr[i + 1] += bsums[i / SCAN_ELEMS];
}

// ---------------- CSR fill: slot = rowptr[dst] + cursor[dst]++, store (src, norm) ----------------
__global__ void fill_kernel(const int* __restrict__ src, const int* __restrict__ dst,
                            const int* __restrict__ rowptr, int* cursor,
                            const float* __restrict__ dinv, int2* __restrict__ csr, int e) {
    int i = blockIdx.x * blockDim.x + threadIdx.x;
    if (i >= e) return;
    int s = src[i];
    int d = dst[i];
    int p = atomicAdd(&cursor[d], 1);
    float nrm = dinv[s] * dinv[d];
    int2 v;
    v.x = s;
    v.y = __float_as_int(nrm);
    csr[rowptr[d] + p] = v;
}

// ---------------- t[n,32] = x[n,128] @ W[128,32] ----------------
__global__ void gemm128_32_kernel(const float* __restrict__ x, const float* __restrict__ W,
                                  float* __restrict__ t, int n) {
    __shared__ float Wl[128 * 32];
    for (int i = threadIdx.x; i < 128 * 32; i += blockDim.x) Wl[i] = W[i];
    __syncthreads();
    int node = blockIdx.x * blockDim.x + threadIdx.x;
    if (node >= n) return;
    float acc[32];
#pragma unroll
    for (int k = 0; k < 32; k++) acc[k] = 0.f;
    const float4* xp = (const float4*)(x + (long long)node * 128);
    for (int j4 = 0; j4 < 32; j4++) {
        float4 v4 = xp[j4];
        float vv[4] = {v4.x, v4.y, v4.z, v4.w};
#pragma unroll
        for (int c = 0; c < 4; c++) {
            const float* wr = &Wl[(j4 * 4 + c) * 32];
#pragma unroll
            for (int k = 0; k < 32; k++) acc[k] += vv[c] * wr[k];
        }
    }
    float4* op = (float4*)(t + (long long)node * 32);
#pragma unroll
    for (int k4 = 0; k4 < 8; k4++)
        op[k4] = make_float4(acc[4 * k4], acc[4 * k4 + 1], acc[4 * k4 + 2], acc[4 * k4 + 3]);
}

// ---------------- t[n,32] = xin[n,32] @ W[32,32] ----------------
__global__ void gemm32_32_kernel(const float* __restrict__ xin, const float* __restrict__ W,
                                 float* __restrict__ t, int n) {
    __shared__ float Wl[32 * 32];
    for (int i = threadIdx.x; i < 32 * 32; i += blockDim.x) Wl[i] = W[i];
    __syncthreads();
    int node = blockIdx.x * blockDim.x + threadIdx.x;
    if (node >= n) return;
    float acc[32];
#pragma unroll
    for (int k = 0; k < 32; k++) acc[k] = 0.f;
    const float4* xp = (const float4*)(xin + (long long)node * 32);
#pragma unroll
    for (int j4 = 0; j4 < 8; j4++) {
        float4 v4 = xp[j4];
        float vv[4] = {v4.x, v4.y, v4.z, v4.w};
#pragma unroll
        for (int c = 0; c < 4; c++) {
            const float* wr = &Wl[(j4 * 4 + c) * 32];
#pragma unroll
            for (int k = 0; k < 32; k++) acc[k] += vv[c] * wr[k];
        }
    }
    float4* op = (float4*)(t + (long long)node * 32);
#pragma unroll
    for (int k4 = 0; k4 < 8; k4++)
        op[k4] = make_float4(acc[4 * k4], acc[4 * k4 + 1], acc[4 * k4 + 2], acc[4 * k4 + 3]);
}

// ---------------- pull-mode aggregation + bias + relu ----------------
// 32 lanes per node (lane = feature), 8 nodes per 256-thread block.
__global__ void gather_kernel(const int* __restrict__ rowptr, const int2* __restrict__ csr,
                              const float* __restrict__ dinv, const float* __restrict__ t,
                              const float* __restrict__ bias, float* __restrict__ xo, int n) {
    int tid = blockIdx.x * blockDim.x + threadIdx.x;
    int node = tid >> 5;
    int k = tid & 31;
    if (node >= n) return;
    float d = dinv[node];
    float acc = t[node * 32 + k] * d * d;  // self-loop term
    int beg = rowptr[node];
    int end = rowptr[node + 1];
    for (int e = beg; e < end; e++) {
        int2 sn = csr[e];
        acc += t[sn.x * 32 + k] * __int_as_float(sn.y);
    }
    xo[node * 32 + k] = fmaxf(acc + bias[k], 0.f);
}

// ---------------- h64 = relu(concat(x1,x2,x3) @ fc1_w + fc1_b) ----------------
__global__ void fc1_kernel(const float* __restrict__ x1, const float* __restrict__ x2,
                           const float* __restrict__ x3, const float* __restrict__ W,
                           const float* __restrict__ b, float* __restrict__ h64, int n) {
    __shared__ float Wl[96 * 64];
    for (int i = threadIdx.x; i < 96 * 64; i += blockDim.x) Wl[i] = W[i];
    __syncthreads();
    int node = blockIdx.x * blockDim.x + threadIdx.x;
    if (node >= n) return;
    float acc[64];
#pragma unroll
    for (int k = 0; k < 64; k++) acc[k] = b[k];
    const float* srcs[3] = {x1 + (long long)node * 32, x2 + (long long)node * 32,
                            x3 + (long long)node * 32};
    for (int s = 0; s < 3; s++) {
        const float* xp = srcs[s];
        for (int j = 0; j < 32; j++) {
            float v = xp[j];
            const float* wr = &Wl[(s * 32 + j) * 64];
#pragma unroll
            for (int k = 0; k < 64; k++) acc[k] += v * wr[k];
        }
    }
    float4* op = (float4*)(h64 + (long long)node * 64);
#pragma unroll
    for (int k4 = 0; k4 < 16; k4++)
        op[k4] = make_float4(fmaxf(acc[4 * k4], 0.f), fmaxf(acc[4 * k4 + 1], 0.f),
                             fmaxf(acc[4 * k4 + 2], 0.f), fmaxf(acc[4 * k4 + 3], 0.f));
}

// ---------------- h128 = relu(h64 @ fc2a_w + fc2a_b) ----------------
__global__ void fc2a_kernel(const float* __restrict__ h64, const float* __restrict__ W,
                            const float* __restrict__ b, float* __restrict__ h128, int n) {
    __shared__ float Wl[64 * 128];
    for (int i = threadIdx.x; i < 64 * 128; i += blockDim.x) Wl[i] = W[i];
    __syncthreads();
    int node = blockIdx.x * blockDim.x + threadIdx.x;
    if (node >= n) return;
    float acc[128];
#pragma unroll
    for (int k = 0; k < 128; k++) acc[k] = b[k];
    const float* xp = h64 + (long long)node * 64;
    for (int j = 0; j < 64; j++) {
        float v = xp[j];
        const float* wr = &Wl[j * 128];
#pragma unroll
        for (int k = 0; k < 128; k++) acc[k] += v * wr[k];
    }
    float4* op = (float4*)(h128 + (long long)node * 128);
#pragma unroll
    for (int k4 = 0; k4 < 32; k4++)
        op[k4] = make_float4(fmaxf(acc[4 * k4], 0.f), fmaxf(acc[4 * k4 + 1], 0.f),
                             fmaxf(acc[4 * k4 + 2], 0.f), fmaxf(acc[4 * k4 + 3], 0.f));
}

// ---------------- pooled partials: grid (NG, NSPLIT), 128 threads ----------------
__global__ void pool_kernel(const float* __restrict__ h128, const int* __restrict__ batch,
                            float* __restrict__ part, int n) {
    int g = blockIdx.x;
    int sp = blockIdx.y;
    int lo = 0, hi = n;
    while (lo < hi) {
        int mid = (lo + hi) >> 1;
        if (batch[mid] < g) lo = mid + 1; else hi = mid;
    }
    int start = lo;
    lo = start; hi = n;
    while (lo < hi) {
        int mid = (lo + hi) >> 1;
        if (batch[mid] < g + 1) lo = mid + 1; else hi = mid;
    }
    int end = lo;
    int k = threadIdx.x;  // 128
    float s = 0.f;
    for (int i = start + sp; i < end; i += NSPLIT) s += h128[(long long)i * 128 + k];
    part[((long long)g * NSPLIT + sp) * 128 + k] = s;
}

// ---------------- head: sum partials -> relu(fc2b) -> fc3 -> log_softmax ----------------
__global__ void head_kernel(const float* __restrict__ part, const float* __restrict__ W2b,
                            const float* __restrict__ b2b, const float* __restrict__ W3,
                            const float* __restrict__ b3, float* __restrict__ out) {
    __shared__ float Wl[128 * 64];
    for (int i = threadIdx.x; i < 128 * 64; i += blockDim.x) Wl[i] = W2b[i];
    __syncthreads();
    int g = blockIdx.x * blockDim.x + threadIdx.x;
    if (g >= NG) return;
    float acc[64];
#pragma unroll
    for (int k = 0; k < 64; k++) acc[k] = b2b[k];
    const float* p0 = part + (long long)g * NSPLIT * 128;
    for (int j = 0; j < 128; j++) {
        float v = p0[j] + p0[128 + j] + p0[256 + j] + p0[384 + j];
        const float* wr = &Wl[j * 64];
#pragma unroll
        for (int k = 0; k < 64; k++) acc[k] += v * wr[k];
    }
    float l0 = b3[0], l1 = b3[1];
#pragma unroll
    for (int k = 0; k < 64; k++) {
        float h = fmaxf(acc[k], 0.f);
        l0 += h * W3[k * 2 + 0];
        l1 += h * W3[k * 2 + 1];
    }
    float m = fmaxf(l0, l1);
    float lse = m + logf(expf(l0 - m) + expf(l1 - m));
    out[g * 2 + 0] = l0 - lse;
    out[g * 2 + 1] = l1 - lse;
}

extern "C" void kernel_launch(void* const* d_in, const int* in_sizes, int n_in,
                              void* d_out, int out_size, void* d_ws, size_t ws_size,
                              hipStream_t stream) {
    const float* x     = (const float*)d_in[0];
    const int*   ei    = (const int*)d_in[1];
    const int*   srcI  = ei;
    const int*   dstI  = ei + NE;
    const int*   batch = (const int*)d_in[2];
    const float* W1    = (const float*)d_in[3];
    const float* b1    = (const float*)d_in[4];
    const float* W2    = (const float*)d_in[5];
    const float* b2    = (const float*)d_in[6];
    const float* W3w   = (const float*)d_in[7];
    const float* b3w   = (const float*)d_in[8];
    const float* fc1w  = (const float*)d_in[9];
    const float* fc1b  = (const float*)d_in[10];
    const float* fc2aw = (const float*)d_in[11];
    const float* fc2ab = (const float*)d_in[12];
    const float* fc2bw = (const float*)d_in[13];
    const float* fc2bb = (const float*)d_in[14];
    const float* fc3w  = (const float*)d_in[15];
    const float* fc3b  = (const float*)d_in[16];
    float* out = (float*)d_out;

    // ---- workspace layout (all offsets 16B-aligned) ----
    char* p = (char*)d_ws;
    int2* csr = (int2*)p;                 p += (size_t)NE * 8;          // 25.6 MB
    int* deg_i = (int*)p;                 p += (size_t)NN * 4;          // 0.4 MB
    int* cursor = (int*)p;                p += (size_t)NN * 4;          // 0.4 MB
    int* rowptr = (int*)p;                p += (size_t)(NN + 4) * 4;    // 0.4 MB
    int* bsums = (int*)p;                 p += 4096;
    float* dinv = (float*)p;              p += (size_t)NN * 4;          // 0.4 MB
    float* t  = (float*)p;                p += (size_t)NN * 32 * 4;     // 12.8 MB
    float* x1 = (float*)p;                p += (size_t)NN * 32 * 4;
    float* x2 = (float*)p;                p += (size_t)NN * 32 * 4;
    float* x3 = (float*)p;                p += (size_t)NN * 32 * 4;
    float* part = (float*)p;              p += (size_t)NG * NSPLIT * 128 * 4;  // 1 MB
    float* h64 = (float*)csr;             // alias: CSR dead after layer 3
    float* h128 = t;                      // alias: t..x3 (51.2 MB) dead after fc1

    const int thr = 256;
    int gN  = (NN + thr - 1) / thr;
    int gE  = (NE + thr - 1) / thr;
    int gNd = (NN * 32 / 32 + thr - 1) / thr;  // nodes*32 threads / block
    int gGather = (NN * 32 + thr - 1) / thr;

    // ---- CSR build ----
    zero2_kernel<<<gN, thr, 0, stream>>>(deg_i, cursor, NN);
    deg_count_kernel<<<gE, thr, 0, stream>>>(dstI, deg_i, NE);
    scan1_kernel<<<NBLK, SCAN_BLOCK, 0, stream>>>(deg_i, rowptr, bsums, NN);
    scan2_kernel<<<1, 64, 0, stream>>>(bsums, NBLK);
    scan3_kernel<<<gN, thr, 0, stream>>>(rowptr, bsums, NN);
    dinv_kernel<<<gN, thr, 0, stream>>>(deg_i, dinv, NN);
    fill_kernel<<<gE, thr, 0, stream>>>(srcI, dstI, rowptr, cursor, dinv, csr, NE);

    // ---- conv layers (transform -> gather+bias+relu) ----
    gemm128_32_kernel<<<gN, thr, 0, stream>>>(x, W1, t, NN);
    gather_kernel<<<gGather, thr, 0, stream>>>(rowptr, csr, dinv, t, b1, x1, NN);

    gemm32_32_kernel<<<gN, thr, 0, stream>>>(x1, W2, t, NN);
    gather_kernel<<<gGather, thr, 0, stream>>>(rowptr, csr, dinv, t, b2, x2, NN);

    gemm32_32_kernel<<<gN, thr, 0, stream>>>(x2, W3w, t, NN);
    gather_kernel<<<gGather, thr, 0, stream>>>(rowptr, csr, dinv, t, b3w, x3, NN);

    // ---- MLP head ----
    fc1_kernel<<<gN, thr, 0, stream>>>(x1, x2, x3, fc1w, fc1b, h64, NN);
    fc2a_kernel<<<gN, thr, 0, stream>>>(h64, fc2aw, fc2ab, h128, NN);

    // ---- pooling + classifier ----
    dim3 pg(NG, NSPLIT);
    pool_kernel<<<pg, 128, 0, stream>>>(h128, batch, part, NN);
    head_kernel<<<(NG + thr - 1) / thr, thr, 0, stream>>>(part, fc2bw, fc2bb, fc3w, fc3b, out);
    (void)gNd; (void)ws_size; (void)in_sizes; (void)n_in; (void)out_size;
}

// Round 3
// 1107.930 us; speedup vs baseline: 1.4549x; 1.0786x over previous
//
#include <hip/hip_runtime.h>
#include <math.h>

#define NN 100000
#define NE 3200000
#define NG 512
#define NSPLIT 4
#define SCAN_BLOCK 256
#define SCAN_ELEMS 1024
#define NBLK ((NN + SCAN_ELEMS - 1) / SCAN_ELEMS)

// ---------------- zero int arrays ----------------
__global__ void zero2_kernel(int* a, int* b, int n) {
    int i = blockIdx.x * blockDim.x + threadIdx.x;
    if (i < n) { a[i] = 0; b[i] = 0; }
}

// ---------------- int degree histogram over dst ----------------
__global__ void deg_count_kernel(const int* __restrict__ dst, int* deg, int e) {
    int i = blockIdx.x * blockDim.x + threadIdx.x;
    if (i < e) atomicAdd(&deg[dst[i]], 1);
}

// ---------------- dinv = rsqrt(deg_edges + 1)  (self-loop) ----------------
__global__ void dinv_kernel(const int* __restrict__ deg, float* dinv, int n) {
    int i = blockIdx.x * blockDim.x + threadIdx.x;
    if (i < n) dinv[i] = rsqrtf((float)(deg[i] + 1));
}

// ---------------- scan pass 1 ----------------
__global__ void scan1_kernel(const int* __restrict__ deg, int* __restrict__ rowptr,
                             int* __restrict__ bsums, int n) {
    __shared__ int lds[SCAN_BLOCK];
    int base = blockIdx.x * SCAN_ELEMS;
    int t = threadIdx.x;
    int v[4];
    int s = 0;
#pragma unroll
    for (int j = 0; j < 4; j++) {
        int i = base + t * 4 + j;
        v[j] = (i < n) ? deg[i] : 0;
        s += v[j];
    }
    lds[t] = s;
    __syncthreads();
    for (int off = 1; off < SCAN_BLOCK; off <<= 1) {
        int val = (t >= off) ? lds[t - off] : 0;
        __syncthreads();
        lds[t] += val;
        __syncthreads();
    }
    int run = (t > 0) ? lds[t - 1] : 0;
    if (t == SCAN_BLOCK - 1) bsums[blockIdx.x] = lds[t];
#pragma unroll
    for (int j = 0; j < 4; j++) {
        int i = base + t * 4 + j;
        run += v[j];
        if (i < n) rowptr[i + 1] = run;
    }
}

// ---------------- scan pass 2 ----------------
__global__ void scan2_kernel(int* bsums, int nb) {
    if (threadIdx.x == 0 && blockIdx.x == 0) {
        int acc = 0;
        for (int b = 0; b < nb; b++) { int v = bsums[b]; bsums[b] = acc; acc += v; }
    }
}

// ---------------- scan pass 3 ----------------
__global__ void scan3_kernel(int* rowptr, const int* __restrict__ bsums, int n) {
    int i = blockIdx.x * blockDim.x + threadIdx.x;
    if (i == 0) rowptr[0] = 0;
    if (i < n) rowptr[i + 1] += bsums[i / SCAN_ELEMS];
}

// ---------------- CSR fill ----------------
__global__ void fill_kernel(const int* __restrict__ src, const int* __restrict__ dst,
                            const int* __restrict__ rowptr, int* cursor,
                            const float* __restrict__ dinv, int2* __restrict__ csr, int e) {
    int i = blockIdx.x * blockDim.x + threadIdx.x;
    if (i >= e) return;
    int s = src[i];
    int d = dst[i];
    int p = atomicAdd(&cursor[d], 1);
    float nrm = dinv[s] * dinv[d];
    int2 v;
    v.x = s;
    v.y = __float_as_int(nrm);
    csr[rowptr[d] + p] = v;
}

// ---------------- t[n,32] = x[n,128] @ W[128,32] ----------------
__global__ void gemm128_32_kernel(const float* __restrict__ x, const float* __restrict__ W,
                                  float* __restrict__ t, int n) {
    __shared__ float Wl[128 * 32];
    for (int i = threadIdx.x; i < 128 * 32; i += blockDim.x) Wl[i] = W[i];
    __syncthreads();
    int node = blockIdx.x * blockDim.x + threadIdx.x;
    if (node >= n) return;
    float acc[32];
#pragma unroll
    for (int k = 0; k < 32; k++) acc[k] = 0.f;
    const float4* xp = (const float4*)(x + (long long)node * 128);
    for (int j4 = 0; j4 < 32; j4++) {
        float4 v4 = xp[j4];
        float vv[4] = {v4.x, v4.y, v4.z, v4.w};
#pragma unroll
        for (int c = 0; c < 4; c++) {
            const float* wr = &Wl[(j4 * 4 + c) * 32];
#pragma unroll
            for (int k = 0; k < 32; k++) acc[k] += vv[c] * wr[k];
        }
    }
    float4* op = (float4*)(t + (long long)node * 32);
#pragma unroll
    for (int k4 = 0; k4 < 8; k4++)
        op[k4] = make_float4(acc[4 * k4], acc[4 * k4 + 1], acc[4 * k4 + 2], acc[4 * k4 + 3]);
}

// ---------------- t[n,32] = xin[n,32] @ W[32,32] ----------------
__global__ void gemm32_32_kernel(const float* __restrict__ xin, const float* __restrict__ W,
                                 float* __restrict__ t, int n) {
    __shared__ float Wl[32 * 32];
    for (int i = threadIdx.x; i < 32 * 32; i += blockDim.x) Wl[i] = W[i];
    __syncthreads();
    int node = blockIdx.x * blockDim.x + threadIdx.x;
    if (node >= n) return;
    float acc[32];
#pragma unroll
    for (int k = 0; k < 32; k++) acc[k] = 0.f;
    const float4* xp = (const float4*)(xin + (long long)node * 32);
#pragma unroll
    for (int j4 = 0; j4 < 8; j4++) {
        float4 v4 = xp[j4];
        float vv[4] = {v4.x, v4.y, v4.z, v4.w};
#pragma unroll
        for (int c = 0; c < 4; c++) {
            const float* wr = &Wl[(j4 * 4 + c) * 32];
#pragma unroll
            for (int k = 0; k < 32; k++) acc[k] += vv[c] * wr[k];
        }
    }
    float4* op = (float4*)(t + (long long)node * 32);
#pragma unroll
    for (int k4 = 0; k4 < 8; k4++)
        op[k4] = make_float4(acc[4 * k4], acc[4 * k4 + 1], acc[4 * k4 + 2], acc[4 * k4 + 3]);
}

// ---------------- pull-mode aggregation + bias + relu ----------------
__global__ void gather_kernel(const int* __restrict__ rowptr, const int2* __restrict__ csr,
                              const float* __restrict__ dinv, const float* __restrict__ t,
                              const float* __restrict__ bias, float* __restrict__ xo, int n) {
    int tid = blockIdx.x * blockDim.x + threadIdx.x;
    int node = tid >> 5;
    int k = tid & 31;
    if (node >= n) return;
    float d = dinv[node];
    float acc = t[node * 32 + k] * d * d;  // self-loop term
    int beg = rowptr[node];
    int end = rowptr[node + 1];
    for (int e = beg; e < end; e++) {
        int2 sn = csr[e];
        acc += t[sn.x * 32 + k] * __int_as_float(sn.y);
    }
    xo[node * 32 + k] = fmaxf(acc + bias[k], 0.f);
}

// ---------------- fused head: fc1 + fc2a + pool partials ----------------
// grid (NG, NSPLIT), 256 threads. Processes 4 nodes per iteration, three
// LDS-staged phases. pooled partial kept in 2 regs/thread (no spill).
__global__ __launch_bounds__(256) void head_fused_kernel(
    const float* __restrict__ x1, const float* __restrict__ x2, const float* __restrict__ x3,
    const float* __restrict__ W1f, const float* __restrict__ b1f,
    const float* __restrict__ W2f, const float* __restrict__ b2f,
    const int* __restrict__ batch, float* __restrict__ part, int n) {
    __shared__ float W1l[96 * 64];    // 24 KB
    __shared__ float W2l[64 * 128];   // 32 KB
    __shared__ float b1l[64];
    __shared__ float b2l[128];
    __shared__ float xrow[4][96];
    __shared__ float h64s[4][64];
    __shared__ float red[256][2];
    int t = threadIdx.x;
    for (int i = t; i < 96 * 64; i += 256) W1l[i] = W1f[i];
    for (int i = t; i < 64 * 128; i += 256) W2l[i] = W2f[i];
    if (t < 64) b1l[t] = b1f[t];
    else if (t < 192) b2l[t - 64] = b2f[t - 64];
    int g = blockIdx.x;
    int sp = blockIdx.y;
    // graph node range via binary search on sorted batch
    int lo = 0, hi = n;
    while (lo < hi) { int m = (lo + hi) >> 1; if (batch[m] < g) lo = m + 1; else hi = m; }
    int start = lo;
    hi = n;
    while (lo < hi) { int m = (lo + hi) >> 1; if (batch[m] <= g) lo = m + 1; else hi = m; }
    int end = lo;
    int len = end - start;
    int chunk = (len + NSPLIT - 1) / NSPLIT;
    int s0 = start + sp * chunk;
    int s1 = min(s0 + chunk, end);
    float accx = 0.f, accy = 0.f;
    __syncthreads();
    for (int i0 = s0; i0 < s1; i0 += 4) {
        // phase A: stage up to 4 node rows (96 floats each), coalesced
        for (int idx = t; idx < 4 * 96; idx += 256) {
            int nd = idx / 96, j = idx - nd * 96;
            int node = i0 + nd;
            float v = 0.f;
            if (node < s1)
                v = (j < 32) ? x1[node * 32 + j]
                  : (j < 64) ? x2[node * 32 + (j - 32)]
                             : x3[node * 32 + (j - 64)];
            xrow[nd][j] = v;
        }
        __syncthreads();
        // phase B: h64 = relu(xrow @ W1 + b1); wave = one node (t>>6)
        {
            int nd = t >> 6, c = t & 63;
            float s = b1l[c];
#pragma unroll 8
            for (int j = 0; j < 96; j++) s += xrow[nd][j] * W1l[j * 64 + c];
            h64s[nd][c] = fmaxf(s, 0.f);
        }
        __syncthreads();
        // phase C: h128 cols (2 per thread) + pooled accumulate
        {
            int nd = t >> 6, c0 = (t & 63) * 2;
            float sa = b2l[c0], sb = b2l[c0 + 1];
#pragma unroll 8
            for (int j = 0; j < 64; j++) {
                float hv = h64s[nd][j];
                float2 w = *(const float2*)&W2l[j * 128 + c0];
                sa += hv * w.x;
                sb += hv * w.y;
            }
            if (i0 + nd < s1) { accx += fmaxf(sa, 0.f); accy += fmaxf(sb, 0.f); }
        }
        __syncthreads();
    }
    red[t][0] = accx;
    red[t][1] = accy;
    __syncthreads();
    if (t < 64) {
        int c0 = t * 2;
        float p0 = red[t][0] + red[64 + t][0] + red[128 + t][0] + red[192 + t][0];
        float p1 = red[t][1] + red[64 + t][1] + red[128 + t][1] + red[192 + t][1];
        float* dst = part + ((long long)g * NSPLIT + sp) * 128;
        dst[c0] = p0;
        dst[c0 + 1] = p1;
    }
}

// ---------------- head: sum partials -> relu(fc2b) -> fc3 -> log_softmax ----------------
__global__ void head_kernel(const float* __restrict__ part, const float* __restrict__ W2b,
                            const float* __restrict__ b2b, const float* __restrict__ W3,
                            const float* __restrict__ b3, float* __restrict__ out) {
    __shared__ float Wl[128 * 64];
    for (int i = threadIdx.x; i < 128 * 64; i += blockDim.x) Wl[i] = W2b[i];
    __syncthreads();
    int g = blockIdx.x * blockDim.x + threadIdx.x;
    if (g >= NG) return;
    float acc[64];
#pragma unroll
    for (int k = 0; k < 64; k++) acc[k] = b2b[k];
    const float* p0 = part + (long long)g * NSPLIT * 128;
    for (int j = 0; j < 128; j++) {
        float v = p0[j] + p0[128 + j] + p0[256 + j] + p0[384 + j];
        const float* wr = &Wl[j * 64];
#pragma unroll
        for (int k = 0; k < 64; k++) acc[k] += v * wr[k];
    }
    float l0 = b3[0], l1 = b3[1];
#pragma unroll
    for (int k = 0; k < 64; k++) {
        float h = fmaxf(acc[k], 0.f);
        l0 += h * W3[k * 2 + 0];
        l1 += h * W3[k * 2 + 1];
    }
    float m = fmaxf(l0, l1);
    float lse = m + logf(expf(l0 - m) + expf(l1 - m));
    out[g * 2 + 0] = l0 - lse;
    out[g * 2 + 1] = l1 - lse;
}

extern "C" void kernel_launch(void* const* d_in, const int* in_sizes, int n_in,
                              void* d_out, int out_size, void* d_ws, size_t ws_size,
                              hipStream_t stream) {
    const float* x     = (const float*)d_in[0];
    const int*   ei    = (const int*)d_in[1];
    const int*   srcI  = ei;
    const int*   dstI  = ei + NE;
    const int*   batch = (const int*)d_in[2];
    const float* W1    = (const float*)d_in[3];
    const float* b1    = (const float*)d_in[4];
    const float* W2    = (const float*)d_in[5];
    const float* b2    = (const float*)d_in[6];
    const float* W3w   = (const float*)d_in[7];
    const float* b3w   = (const float*)d_in[8];
    const float* fc1w  = (const float*)d_in[9];
    const float* fc1b  = (const float*)d_in[10];
    const float* fc2aw = (const float*)d_in[11];
    const float* fc2ab = (const float*)d_in[12];
    const float* fc2bw = (const float*)d_in[13];
    const float* fc2bb = (const float*)d_in[14];
    const float* fc3w  = (const float*)d_in[15];
    const float* fc3b  = (const float*)d_in[16];
    float* out = (float*)d_out;

    // ---- workspace layout ----
    char* p = (char*)d_ws;
    int2* csr = (int2*)p;                 p += (size_t)NE * 8;          // 25.6 MB
    int* deg_i = (int*)p;                 p += (size_t)NN * 4;
    int* cursor = (int*)p;                p += (size_t)NN * 4;
    int* rowptr = (int*)p;                p += (size_t)(NN + 4) * 4;
    int* bsums = (int*)p;                 p += 4096;
    float* dinv = (float*)p;              p += (size_t)NN * 4;
    float* t  = (float*)p;                p += (size_t)NN * 32 * 4;     // 12.8 MB
    float* x1 = (float*)p;                p += (size_t)NN * 32 * 4;
    float* x2 = (float*)p;                p += (size_t)NN * 32 * 4;
    float* x3 = (float*)p;                p += (size_t)NN * 32 * 4;
    float* part = (float*)p;              p += (size_t)NG * NSPLIT * 128 * 4;

    const int thr = 256;
    int gN  = (NN + thr - 1) / thr;
    int gE  = (NE + thr - 1) / thr;
    int gGather = (NN * 32 + thr - 1) / thr;

    // ---- CSR build ----
    zero2_kernel<<<gN, thr, 0, stream>>>(deg_i, cursor, NN);
    deg_count_kernel<<<gE, thr, 0, stream>>>(dstI, deg_i, NE);
    scan1_kernel<<<NBLK, SCAN_BLOCK, 0, stream>>>(deg_i, rowptr, bsums, NN);
    scan2_kernel<<<1, 64, 0, stream>>>(bsums, NBLK);
    scan3_kernel<<<gN, thr, 0, stream>>>(rowptr, bsums, NN);
    dinv_kernel<<<gN, thr, 0, stream>>>(deg_i, dinv, NN);
    fill_kernel<<<gE, thr, 0, stream>>>(srcI, dstI, rowptr, cursor, dinv, csr, NE);

    // ---- conv layers ----
    gemm128_32_kernel<<<gN, thr, 0, stream>>>(x, W1, t, NN);
    gather_kernel<<<gGather, thr, 0, stream>>>(rowptr, csr, dinv, t, b1, x1, NN);

    gemm32_32_kernel<<<gN, thr, 0, stream>>>(x1, W2, t, NN);
    gather_kernel<<<gGather, thr, 0, stream>>>(rowptr, csr, dinv, t, b2, x2, NN);

    gemm32_32_kernel<<<gN, thr, 0, stream>>>(x2, W3w, t, NN);
    gather_kernel<<<gGather, thr, 0, stream>>>(rowptr, csr, dinv, t, b3w, x3, NN);

    // ---- fused MLP head + pooling partials ----
    dim3 hg(NG, NSPLIT);
    head_fused_kernel<<<hg, thr, 0, stream>>>(x1, x2, x3, fc1w, fc1b, fc2aw, fc2ab,
                                              batch, part, NN);

    // ---- classifier ----
    head_kernel<<<(NG + thr - 1) / thr, thr, 0, stream>>>(part, fc2bw, fc2bb, fc3w, fc3b, out);
    (void)ws_size; (void)in_sizes; (void)n_in; (void)out_size;
}

// Round 4
// 1007.914 us; speedup vs baseline: 1.5993x; 1.0992x over previous
//
#include <hip/hip_runtime.h>
#include <math.h>

#define NN 100000
#define NE 3200000
#define NG 512
#define SCAN_BLOCK 256
#define SCAN_ELEMS 1024
#define NBLK ((NN + SCAN_ELEMS - 1) / SCAN_ELEMS)

// ---------------- zero int arrays ----------------
__global__ void zero2_kernel(int* a, int* b, int n) {
    int i = blockIdx.x * blockDim.x + threadIdx.x;
    if (i < n) { a[i] = 0; b[i] = 0; }
}

__global__ void zero_pool_kernel(float* p, int n) {
    int i = blockIdx.x * blockDim.x + threadIdx.x;
    if (i < n) p[i] = 0.f;
}

// ---------------- int degree histogram over dst ----------------
__global__ void deg_count_kernel(const int* __restrict__ dst, int* deg, int e) {
    int i = blockIdx.x * blockDim.x + threadIdx.x;
    if (i < e) atomicAdd(&deg[dst[i]], 1);
}

// ---------------- dinv = rsqrt(deg_edges + 1)  (self-loop) ----------------
__global__ void dinv_kernel(const int* __restrict__ deg, float* dinv, int n) {
    int i = blockIdx.x * blockDim.x + threadIdx.x;
    if (i < n) dinv[i] = rsqrtf((float)(deg[i] + 1));
}

// ---------------- scan pass 1 ----------------
__global__ void scan1_kernel(const int* __restrict__ deg, int* __restrict__ rowptr,
                             int* __restrict__ bsums, int n) {
    __shared__ int lds[SCAN_BLOCK];
    int base = blockIdx.x * SCAN_ELEMS;
    int t = threadIdx.x;
    int v[4];
    int s = 0;
#pragma unroll
    for (int j = 0; j < 4; j++) {
        int i = base + t * 4 + j;
        v[j] = (i < n) ? deg[i] : 0;
        s += v[j];
    }
    lds[t] = s;
    __syncthreads();
    for (int off = 1; off < SCAN_BLOCK; off <<= 1) {
        int val = (t >= off) ? lds[t - off] : 0;
        __syncthreads();
        lds[t] += val;
        __syncthreads();
    }
    int run = (t > 0) ? lds[t - 1] : 0;
    if (t == SCAN_BLOCK - 1) bsums[blockIdx.x] = lds[t];
#pragma unroll
    for (int j = 0; j < 4; j++) {
        int i = base + t * 4 + j;
        run += v[j];
        if (i < n) rowptr[i + 1] = run;
    }
}

// ---------------- scan pass 2 ----------------
__global__ void scan2_kernel(int* bsums, int nb) {
    if (threadIdx.x == 0 && blockIdx.x == 0) {
        int acc = 0;
        for (int b = 0; b < nb; b++) { int v = bsums[b]; bsums[b] = acc; acc += v; }
    }
}

// ---------------- scan pass 3 ----------------
__global__ void scan3_kernel(int* rowptr, const int* __restrict__ bsums, int n) {
    int i = blockIdx.x * blockDim.x + threadIdx.x;
    if (i == 0) rowptr[0] = 0;
    if (i < n) rowptr[i + 1] += bsums[i / SCAN_ELEMS];
}

// ---------------- CSR fill ----------------
__global__ void fill_kernel(const int* __restrict__ src, const int* __restrict__ dst,
                            const int* __restrict__ rowptr, int* cursor,
                            const float* __restrict__ dinv, int2* __restrict__ csr, int e) {
    int i = blockIdx.x * blockDim.x + threadIdx.x;
    if (i >= e) return;
    int s = src[i];
    int d = dst[i];
    int p = atomicAdd(&cursor[d], 1);
    float nrm = dinv[s] * dinv[d];
    int2 v;
    v.x = s;
    v.y = __float_as_int(nrm);
    csr[rowptr[d] + p] = v;
}

// ---------------- t[n,32] = x[n,128] @ W[128,32], 64-node tiles ----------------
__global__ __launch_bounds__(256) void gemm128_32_tiled(
    const float* __restrict__ x, const float* __restrict__ W, float* __restrict__ tout, int n) {
    __shared__ float Wl[128 * 32];   // 16 KB
    __shared__ float Xl[64 * 132];   // 33.8 KB (pad 132 breaks bank alias)
    int t = threadIdx.x;
    for (int i = t; i < 128 * 32; i += 256) Wl[i] = W[i];
    int tile0 = blockIdx.x * 64;
    for (int idx = t; idx < 64 * 128; idx += 256) {
        int r = idx >> 7, k = idx & 127;
        int node = tile0 + r;
        Xl[r * 132 + k] = (node < n) ? x[(long long)node * 128 + k] : 0.f;
    }
    __syncthreads();
    int cg = t & 7, ng = t >> 3;  // 8 col-groups x 4 cols; 32 node-groups x 2 nodes
    int c0 = cg * 4;
    float acc[2][4];
#pragma unroll
    for (int i = 0; i < 2; i++)
        for (int j = 0; j < 4; j++) acc[i][j] = 0.f;
    for (int k = 0; k < 128; k++) {
        float4 w = *(const float4*)&Wl[k * 32 + c0];
#pragma unroll
        for (int i = 0; i < 2; i++) {
            float a = Xl[(ng * 2 + i) * 132 + k];
            acc[i][0] += a * w.x; acc[i][1] += a * w.y;
            acc[i][2] += a * w.z; acc[i][3] += a * w.w;
        }
    }
#pragma unroll
    for (int i = 0; i < 2; i++) {
        int node = tile0 + ng * 2 + i;
        if (node < n)
            *(float4*)&tout[node * 32 + c0] =
                make_float4(acc[i][0], acc[i][1], acc[i][2], acc[i][3]);
    }
}

// ---------------- t[n,32] = xin[n,32] @ W[32,32] ----------------
__global__ void gemm32_32_kernel(const float* __restrict__ xin, const float* __restrict__ W,
                                 float* __restrict__ t, int n) {
    __shared__ float Wl[32 * 32];
    for (int i = threadIdx.x; i < 32 * 32; i += blockDim.x) Wl[i] = W[i];
    __syncthreads();
    int node = blockIdx.x * blockDim.x + threadIdx.x;
    if (node >= n) return;
    float acc[32];
#pragma unroll
    for (int k = 0; k < 32; k++) acc[k] = 0.f;
    const float4* xp = (const float4*)(xin + (long long)node * 32);
#pragma unroll
    for (int j4 = 0; j4 < 8; j4++) {
        float4 v4 = xp[j4];
        float vv[4] = {v4.x, v4.y, v4.z, v4.w};
#pragma unroll
        for (int c = 0; c < 4; c++) {
            const float* wr = &Wl[(j4 * 4 + c) * 32];
#pragma unroll
            for (int k = 0; k < 32; k++) acc[k] += vv[c] * wr[k];
        }
    }
    float4* op = (float4*)(t + (long long)node * 32);
#pragma unroll
    for (int k4 = 0; k4 < 8; k4++)
        op[k4] = make_float4(acc[4 * k4], acc[4 * k4 + 1], acc[4 * k4 + 2], acc[4 * k4 + 3]);
}

// ---------------- pull-mode aggregation + bias + relu ----------------
__global__ void gather_kernel(const int* __restrict__ rowptr, const int2* __restrict__ csr,
                              const float* __restrict__ dinv, const float* __restrict__ t,
                              const float* __restrict__ bias, float* __restrict__ xo, int n) {
    int tid = blockIdx.x * blockDim.x + threadIdx.x;
    int node = tid >> 5;
    int k = tid & 31;
    if (node >= n) return;
    float d = dinv[node];
    float acc = t[node * 32 + k] * d * d;  // self-loop term
    int beg = rowptr[node];
    int end = rowptr[node + 1];
    for (int e = beg; e < end; e++) {
        int2 sn = csr[e];
        acc += t[sn.x * 32 + k] * __int_as_float(sn.y);
    }
    xo[node * 32 + k] = fmaxf(acc + bias[k], 0.f);
}

// ---------------- h64 = relu(concat(x1,x2,x3) @ fc1_w + fc1_b), 64-node tiles ----------------
__global__ __launch_bounds__(256) void fc1_tiled_kernel(
    const float* __restrict__ x1, const float* __restrict__ x2, const float* __restrict__ x3,
    const float* __restrict__ W, const float* __restrict__ b, float* __restrict__ h64, int n) {
    __shared__ float Wl[96 * 64];   // 24 KB
    __shared__ float Xl[64][97];    // 24.8 KB
    int t = threadIdx.x;
    for (int i = t; i < 96 * 64; i += 256) Wl[i] = W[i];
    int tile0 = blockIdx.x * 64;
    for (int idx = t; idx < 64 * 32; idx += 256) {
        int r = idx >> 5, j = idx & 31;
        int node = tile0 + r;
        float v1 = 0.f, v2 = 0.f, v3 = 0.f;
        if (node < n) {
            v1 = x1[node * 32 + j];
            v2 = x2[node * 32 + j];
            v3 = x3[node * 32 + j];
        }
        Xl[r][j] = v1; Xl[r][32 + j] = v2; Xl[r][64 + j] = v3;
    }
    __syncthreads();
    int cg = t & 15, ng = t >> 4;  // 16 col-groups x 4 cols; 16 node-groups x 4 nodes
    int c0 = cg * 4;
    float4 bb = *(const float4*)&b[c0];
    float acc[4][4];
#pragma unroll
    for (int i = 0; i < 4; i++) {
        acc[i][0] = bb.x; acc[i][1] = bb.y; acc[i][2] = bb.z; acc[i][3] = bb.w;
    }
    for (int k = 0; k < 96; k++) {
        float4 w = *(const float4*)&Wl[k * 64 + c0];
#pragma unroll
        for (int i = 0; i < 4; i++) {
            float a = Xl[ng * 4 + i][k];
            acc[i][0] += a * w.x; acc[i][1] += a * w.y;
            acc[i][2] += a * w.z; acc[i][3] += a * w.w;
        }
    }
#pragma unroll
    for (int i = 0; i < 4; i++) {
        int node = tile0 + ng * 4 + i;
        if (node < n)
            *(float4*)&h64[node * 64 + c0] =
                make_float4(fmaxf(acc[i][0], 0.f), fmaxf(acc[i][1], 0.f),
                            fmaxf(acc[i][2], 0.f), fmaxf(acc[i][3], 0.f));
    }
}

// ---------------- h128 = relu(h64 @ fc2a_w + b) fused with segment pooling ----------------
__global__ __launch_bounds__(256) void fc2a_pool_kernel(
    const float* __restrict__ h64, const float* __restrict__ W, const float* __restrict__ b,
    const int* __restrict__ batch, float* __restrict__ pooled, int n) {
    __shared__ float Wl[64 * 128];  // 32 KB
    __shared__ float Al[64 * 64];   // 16 KB
    __shared__ int batchl[64];
    int t = threadIdx.x;
    for (int i = t; i < 64 * 128; i += 256) Wl[i] = W[i];
    int tile0 = blockIdx.x * 64;
    for (int idx = t; idx < 64 * 64; idx += 256) {
        int r = idx >> 6, k = idx & 63;
        int node = tile0 + r;
        Al[idx] = (node < n) ? h64[node * 64 + k] : 0.f;
    }
    if (t < 64) batchl[t] = (tile0 + t < n) ? batch[tile0 + t] : -1;
    __syncthreads();
    int cg = t & 31, ng = t >> 5;  // 32 col-groups x 4 cols; 8 node-groups x 8 nodes
    int c0 = cg * 4;
    float acc[8][4];
#pragma unroll
    for (int i = 0; i < 8; i++)
        for (int j = 0; j < 4; j++) acc[i][j] = 0.f;
    for (int k = 0; k < 64; k++) {
        float4 w = *(const float4*)&Wl[k * 128 + c0];
#pragma unroll
        for (int i = 0; i < 8; i++) {
            float a = Al[(ng * 8 + i) * 64 + k];
            acc[i][0] += a * w.x; acc[i][1] += a * w.y;
            acc[i][2] += a * w.z; acc[i][3] += a * w.w;
        }
    }
    float4 bb = *(const float4*)&b[c0];
    int base = ng * 8;
    if (tile0 + base < n) {
        float r0 = 0.f, r1 = 0.f, r2 = 0.f, r3 = 0.f;
        int curg = batchl[base];
        for (int i = 0; i < 8; i++) {
            int node = tile0 + base + i;
            if (node >= n) break;
            int gi = batchl[base + i];
            if (gi != curg) {
                float* dst = pooled + (long long)curg * 128 + c0;
                atomicAdd(dst + 0, r0); atomicAdd(dst + 1, r1);
                atomicAdd(dst + 2, r2); atomicAdd(dst + 3, r3);
                r0 = r1 = r2 = r3 = 0.f;
                curg = gi;
            }
            r0 += fmaxf(acc[i][0] + bb.x, 0.f);
            r1 += fmaxf(acc[i][1] + bb.y, 0.f);
            r2 += fmaxf(acc[i][2] + bb.z, 0.f);
            r3 += fmaxf(acc[i][3] + bb.w, 0.f);
        }
        float* dst = pooled + (long long)curg * 128 + c0;
        atomicAdd(dst + 0, r0); atomicAdd(dst + 1, r1);
        atomicAdd(dst + 2, r2); atomicAdd(dst + 3, r3);
    }
}

// ---------------- head: relu(pooled@fc2b+b) @ fc3 + b3 -> log_softmax ----------------
__global__ void head_kernel(const float* __restrict__ pooled, const float* __restrict__ W2b,
                            const float* __restrict__ b2b, const float* __restrict__ W3,
                            const float* __restrict__ b3, float* __restrict__ out) {
    __shared__ float Wl[128 * 64];
    for (int i = threadIdx.x; i < 128 * 64; i += blockDim.x) Wl[i] = W2b[i];
    __syncthreads();
    int g = blockIdx.x * blockDim.x + threadIdx.x;
    if (g >= NG) return;
    float acc[64];
#pragma unroll
    for (int k = 0; k < 64; k++) acc[k] = b2b[k];
    const float* p0 = pooled + (long long)g * 128;
    for (int j = 0; j < 128; j++) {
        float v = p0[j];
        const float* wr = &Wl[j * 64];
#pragma unroll
        for (int k = 0; k < 64; k++) acc[k] += v * wr[k];
    }
    float l0 = b3[0], l1 = b3[1];
#pragma unroll
    for (int k = 0; k < 64; k++) {
        float h = fmaxf(acc[k], 0.f);
        l0 += h * W3[k * 2 + 0];
        l1 += h * W3[k * 2 + 1];
    }
    float m = fmaxf(l0, l1);
    float lse = m + logf(expf(l0 - m) + expf(l1 - m));
    out[g * 2 + 0] = l0 - lse;
    out[g * 2 + 1] = l1 - lse;
}

extern "C" void kernel_launch(void* const* d_in, const int* in_sizes, int n_in,
                              void* d_out, int out_size, void* d_ws, size_t ws_size,
                              hipStream_t stream) {
    const float* x     = (const float*)d_in[0];
    const int*   ei    = (const int*)d_in[1];
    const int*   srcI  = ei;
    const int*   dstI  = ei + NE;
    const int*   batch = (const int*)d_in[2];
    const float* W1    = (const float*)d_in[3];
    const float* b1    = (const float*)d_in[4];
    const float* W2    = (const float*)d_in[5];
    const float* b2    = (const float*)d_in[6];
    const float* W3w   = (const float*)d_in[7];
    const float* b3w   = (const float*)d_in[8];
    const float* fc1w  = (const float*)d_in[9];
    const float* fc1b  = (const float*)d_in[10];
    const float* fc2aw = (const float*)d_in[11];
    const float* fc2ab = (const float*)d_in[12];
    const float* fc2bw = (const float*)d_in[13];
    const float* fc2bb = (const float*)d_in[14];
    const float* fc3w  = (const float*)d_in[15];
    const float* fc3b  = (const float*)d_in[16];
    float* out = (float*)d_out;

    // ---- workspace layout ----
    char* p = (char*)d_ws;
    int2* csr = (int2*)p;                 p += (size_t)NE * 8;          // 25.6 MB
    int* deg_i = (int*)p;                 p += (size_t)NN * 4;
    int* cursor = (int*)p;                p += (size_t)NN * 4;
    int* rowptr = (int*)p;                p += (size_t)(NN + 4) * 4;
    int* bsums = (int*)p;                 p += 4096;
    float* dinv = (float*)p;              p += (size_t)NN * 4;
    float* t  = (float*)p;                p += (size_t)NN * 32 * 4;     // 12.8 MB
    float* x1 = (float*)p;                p += (size_t)NN * 32 * 4;
    float* x2 = (float*)p;                p += (size_t)NN * 32 * 4;
    float* x3 = (float*)p;                p += (size_t)NN * 32 * 4;
    float* pooled = (float*)p;            p += (size_t)NG * 128 * 4;    // 256 KB
    float* h64 = (float*)csr;             // alias: CSR dead after layer-3 gather (25.6 MB)

    const int thr = 256;
    int gN  = (NN + thr - 1) / thr;
    int gE  = (NE + thr - 1) / thr;
    int gGather = (NN * 32 + thr - 1) / thr;
    int gTile = (NN + 63) / 64;

    // ---- CSR build ----
    zero2_kernel<<<gN, thr, 0, stream>>>(deg_i, cursor, NN);
    deg_count_kernel<<<gE, thr, 0, stream>>>(dstI, deg_i, NE);
    scan1_kernel<<<NBLK, SCAN_BLOCK, 0, stream>>>(deg_i, rowptr, bsums, NN);
    scan2_kernel<<<1, 64, 0, stream>>>(bsums, NBLK);
    scan3_kernel<<<gN, thr, 0, stream>>>(rowptr, bsums, NN);
    dinv_kernel<<<gN, thr, 0, stream>>>(deg_i, dinv, NN);
    fill_kernel<<<gE, thr, 0, stream>>>(srcI, dstI, rowptr, cursor, dinv, csr, NE);

    // ---- conv layers ----
    gemm128_32_tiled<<<gTile, thr, 0, stream>>>(x, W1, t, NN);
    gather_kernel<<<gGather, thr, 0, stream>>>(rowptr, csr, dinv, t, b1, x1, NN);

    gemm32_32_kernel<<<gN, thr, 0, stream>>>(x1, W2, t, NN);
    gather_kernel<<<gGather, thr, 0, stream>>>(rowptr, csr, dinv, t, b2, x2, NN);

    gemm32_32_kernel<<<gN, thr, 0, stream>>>(x2, W3w, t, NN);
    gather_kernel<<<gGather, thr, 0, stream>>>(rowptr, csr, dinv, t, b3w, x3, NN);

    // ---- MLP head: fc1 -> (fc2a + pool) fused ----
    zero_pool_kernel<<<(NG * 128 + thr - 1) / thr, thr, 0, stream>>>(pooled, NG * 128);
    fc1_tiled_kernel<<<gTile, thr, 0, stream>>>(x1, x2, x3, fc1w, fc1b, h64, NN);
    fc2a_pool_kernel<<<gTile, thr, 0, stream>>>(h64, fc2aw, fc2ab, batch, pooled, NN);

    // ---- classifier ----
    head_kernel<<<(NG + thr - 1) / thr, thr, 0, stream>>>(pooled, fc2bw, fc2bb, fc3w, fc3b, out);
    (void)ws_size; (void)in_sizes; (void)n_in; (void)out_size;
}